// Round 15
// baseline (427.768 us; speedup 1.0000x reference)
//
#include <hip/hip_runtime.h>
#include <math.h>

// Fused TowersMLP, bf16-MFMA, transposed-D, 256-thread / 4-wave, 3 blocks/CU.
// R15 = R14 (green 247us: R7 structure + split lgkm barrier + rcp-silu +
// EPI5/EPI6 fusions; bias in EPILOGUE — bias-fold is POISON, retired)
// + PERSISTENT GRID: 768 blocks (3/CU exactly), each loops over ~10.7
// row-tiles. Cold-start (x-stage, first preloads) paid once per block;
// tile i's tail (final dot, reads part in P) overlaps tile i+1's x-staging
// (writes Q); the part-vs-A1 reuse of P is fenced by the staging barrier.

typedef short s8v __attribute__((ext_vector_type(8)));
typedef float f4v __attribute__((ext_vector_type(4)));
typedef int   i2v __attribute__((ext_vector_type(2)));
typedef int   i4v __attribute__((ext_vector_type(4)));

__device__ __forceinline__ short f2bf(float f) {
    unsigned u = __float_as_uint(f);
    unsigned r = (u + 0x7fffu + ((u >> 16) & 1u)) >> 16;   // RNE
    return (short)r;
}
__device__ __forceinline__ int cvt_pk_bf16(float a, float b) {   // lo=a, hi=b
    int r;
    asm("v_cvt_pk_bf16_f32 %0, %1, %2" : "=v"(r) : "v"(a), "v"(b));
    return r;
}
__device__ __forceinline__ float silu_f(float v) {
    return v * __builtin_amdgcn_rcpf(1.0f + __expf(-v));   // rcp, arg >= 1
}

// lgkm-only barrier (R7 split form — PROVEN; do not combine into one asm).
#define BARRIER() do {                                        \
    asm volatile("s_waitcnt lgkmcnt(0)" ::: "memory");        \
    __builtin_amdgcn_s_barrier();                             \
    __builtin_amdgcn_sched_barrier(0);                        \
} while (0)

// ---- packed weight offsets (bf16 elems), layout [nt][ks][lane(64)][8] ----
#define OFF_BD   0        // 96 x 32   (block-diag w_emb, rows>=72 zero) NT=6 KS=1
#define OFF_TW1  3072     // 256 x 96   NT=16 KS=3
#define OFF_TW2  27648    // 256 x 256  NT=16 KS=8
#define OFF_TW3  93184    // 64 x 256   NT=4  KS=8
#define OFF_INP  109568   // 192 x 64   NT=12 KS=2
#define OFF_OUT  121856   // 64 x 64    NT=4  KS=2
#define OFF_FF1  125952   // 128 x 64   NT=8  KS=2
#define OFF_FF2  134144   // 64 x 128   NT=4  KS=4
#define OFF_HW1  142336   // 160 x 192  NT=10 KS=6
#define OFF_HW2  173056   // 64 x 160   NT=4  KS=5

__global__ void pack_weights(const float* __restrict__ w_emb,
                             const float* __restrict__ tw1, const float* __restrict__ tw2,
                             const float* __restrict__ tw3, const float* __restrict__ inpw,
                             const float* __restrict__ outw, const float* __restrict__ ffw1,
                             const float* __restrict__ ffw2, const float* __restrict__ hw1,
                             const float* __restrict__ hw2, short* __restrict__ dst)
{
    int L = blockIdx.y;
    const float* W; int K, KS, N, off;
    switch (L) {
      case 0: W = w_emb; K = 32;  KS = 1; N = 96;  off = OFF_BD;  break;
      case 1: W = tw1;   K = 72;  KS = 3; N = 256; off = OFF_TW1; break;
      case 2: W = tw2;   K = 256; KS = 8; N = 256; off = OFF_TW2; break;
      case 3: W = tw3;   K = 256; KS = 8; N = 64;  off = OFF_TW3; break;
      case 4: W = inpw;  K = 64;  KS = 2; N = 192; off = OFF_INP; break;
      case 5: W = outw;  K = 64;  KS = 2; N = 64;  off = OFF_OUT; break;
      case 6: W = ffw1;  K = 64;  KS = 2; N = 128; off = OFF_FF1; break;
      case 7: W = ffw2;  K = 128; KS = 4; N = 64;  off = OFF_FF2; break;
      case 8: W = hw1;   K = 192; KS = 6; N = 160; off = OFF_HW1; break;
      default:W = hw2;   K = 160; KS = 5; N = 64;  off = OFF_HW2; break;
    }
    int total = (N >> 4) * KS * 512;
    for (int e = blockIdx.x * blockDim.x + threadIdx.x; e < total; e += gridDim.x * blockDim.x) {
        int nt = e / (KS * 512);
        int r  = e - nt * (KS * 512);
        int ks = r >> 9;
        int q  = r & 511;
        int l  = q >> 3, j = q & 7;
        int n  = nt * 16 + (l & 15);
        int k  = ks * 32 + (l >> 4) * 8 + j;
        float v;
        if (L == 0) {
            int gl = n / 24, jj = n - gl * 24, kk = k - gl * 10;
            v = (n < 72 && kk >= 0 && kk < 10) ? w_emb[jj * 10 + kk] : 0.0f;
        } else {
            v = (k < K) ? W[n * K + k] : 0.0f;
        }
        dst[off + e] = f2bf(v);
    }
}

// ---- weight preload (first-tile fragments held across barriers) ----
template<int KSH> struct PreW { s8v w[KSH]; };

template<int KSH>
__device__ __forceinline__ PreW<KSH> preloadW(const short* __restrict__ Wp,
                                              int lane, int nt, int ksTotal) {
    PreW<KSH> p;
    #pragma unroll
    for (int ks = 0; ks < KSH; ++ks)
        p.w[ks] = *(const s8v*)(Wp + nt * (ksTotal * 512) + ks * 512 + lane * 8);
    return p;
}

// ---- shared epilogue (bias added HERE — never in MFMA C) ----
// EPI: 0 silu->bf16, 1 linear->bf16, 2 f32 +=, 3 f32 = acc+bias+pos_c,
//      4 digits (acc+pos_d, n>=72 zero),
//      5 residual: CH + acc + bias -> flat bf16 [16][200],
//      6 silu(acc+bias) dot hw3 -> f32 partial [16][16]
template<int EPI>
__device__ __forceinline__ void epi_store(f4v acc, f4v bv, int t, int n0, void* Out, int Op,
                                          const float* __restrict__ aux)
{
    if (EPI == 0 || EPI == 1) {
        float v0 = acc[0] + bv[0], v1 = acc[1] + bv[1];
        float v2 = acc[2] + bv[2], v3 = acc[3] + bv[3];
        if (EPI == 0) { v0 = silu_f(v0); v1 = silu_f(v1); v2 = silu_f(v2); v3 = silu_f(v3); }
        i2v pk; pk[0] = cvt_pk_bf16(v0, v1); pk[1] = cvt_pk_bf16(v2, v3);
        *(i2v*)((short*)Out + t * Op + n0) = pk;
    } else if (EPI == 2) {
        f4v* p = (f4v*)((float*)Out + t * Op + n0);
        f4v o = *p;
        #pragma unroll
        for (int i = 0; i < 4; ++i) o[i] += acc[i] + bv[i];
        *p = o;
    } else if (EPI == 3) {
        f4v pc = *(const f4v*)(aux + (t % 3) * 64 + n0);
        f4v o;
        #pragma unroll
        for (int i = 0; i < 4; ++i) o[i] = acc[i] + bv[i] + pc[i];
        *(f4v*)((float*)Out + t * Op + n0) = o;
    } else if (EPI == 4) {
        i2v pk;
        if (n0 < 72) {
            f4v pd = *(const f4v*)(aux + (t % 3) * 72 + n0);
            pk[0] = cvt_pk_bf16(acc[0] + pd[0], acc[1] + pd[1]);
            pk[1] = cvt_pk_bf16(acc[2] + pd[2], acc[3] + pd[3]);
        } else { pk[0] = 0; pk[1] = 0; }
        *(i2v*)((short*)Out + t * Op + n0) = pk;
    } else if (EPI == 5) {
        // aux = CH f32 [48][68]; Out = flat bf16 [16][Op]
        f4v ch = *(const f4v*)(aux + t * 68 + n0);
        int rr = t / 3, cc = t - rr * 3;
        i2v pk;
        pk[0] = cvt_pk_bf16(ch[0] + acc[0] + bv[0], ch[1] + acc[1] + bv[1]);
        pk[1] = cvt_pk_bf16(ch[2] + acc[2] + bv[2], ch[3] + acc[3] + bv[3]);
        *(i2v*)((short*)Out + rr * Op + cc * 64 + n0) = pk;
    } else {
        // aux = hw3 f32[64]; Out = part f32 [16][16] (Op=16)
        f4v w = *(const f4v*)(aux + n0);
        float p = silu_f(acc[0] + bv[0]) * w[0] + silu_f(acc[1] + bv[1]) * w[1]
                + silu_f(acc[2] + bv[2]) * w[2] + silu_f(acc[3] + bv[3]) * w[3];
        ((float*)Out)[t * Op + (n0 >> 2)] = p;
    }
}

// ---- generic transposed MFMA dense layer, preloaded first tile ----
template<int MT, int KS, int EPI>
__device__ __forceinline__ void mfma_T(
    const short* __restrict__ Wp,
    const float* __restrict__ bias,
    const short* A, int Ap, void* Out, int Op, int N,
    const float* __restrict__ aux, int lane, int wid, PreW<KS> pre)
{
    const int l15 = lane & 15, l4 = lane >> 4;
    s8v xf[MT][KS];
    #pragma unroll
    for (int m = 0; m < MT; ++m)
        #pragma unroll
        for (int ks = 0; ks < KS; ++ks)
            xf[m][ks] = *(const s8v*)(A + (m * 16 + l15) * Ap + ks * 32 + l4 * 8);

    s8v wf[KS];
    #pragma unroll
    for (int ks = 0; ks < KS; ++ks) wf[ks] = pre.w[ks];

    const int NT = N >> 4;
    for (int nt = wid; nt < NT; nt += 4) {
        s8v wfn[KS];
        const bool more = (nt + 4) < NT;
        if (more) {
            #pragma unroll
            for (int ks = 0; ks < KS; ++ks)
                wfn[ks] = *(const s8v*)(Wp + (nt + 4) * (KS * 512) + ks * 512 + lane * 8);
        }
        const int n0 = nt * 16 + l4 * 4;
        f4v bv = {0.f, 0.f, 0.f, 0.f};
        if (EPI != 4) bv = *(const f4v*)(bias + n0);
        #pragma unroll
        for (int m = 0; m < MT; ++m) {
            f4v acc = {0.f, 0.f, 0.f, 0.f};
            #pragma unroll
            for (int ks = 0; ks < KS; ++ks)
                acc = __builtin_amdgcn_mfma_f32_16x16x32_bf16(wf[ks], xf[m][ks], acc, 0, 0, 0);
            epi_store<EPI>(acc, bv, m * 16 + l15, n0, Out, Op, aux);
        }
        if (more) {
            #pragma unroll
            for (int ks = 0; ks < KS; ++ks) wf[ks] = wfn[ks];
        }
    }
}

// ---- K-split persistent-acc layer (tw2/tw3), preloaded (kh=0,i=0) group ----
template<int MT, int KSH, int KH, int NTW, int EPI>
__device__ __forceinline__ void mfma_acc(
    const short* __restrict__ Wp, const float* __restrict__ bias,
    const short* A, int Ap, void* Out, int Op,
    const float* __restrict__ aux, int lane, int wid, int ntBase, PreW<KSH> pre)
{
    const int l15 = lane & 15, l4 = lane >> 4;
    const int KS = KSH * KH;
    f4v acc[NTW][MT];
    #pragma unroll
    for (int i = 0; i < NTW; ++i)
        #pragma unroll
        for (int m = 0; m < MT; ++m) acc[i][m] = (f4v){0.f, 0.f, 0.f, 0.f};

    #pragma unroll
    for (int kh = 0; kh < KH; ++kh) {
        s8v xf[MT][KSH];
        #pragma unroll
        for (int m = 0; m < MT; ++m)
            #pragma unroll
            for (int ks = 0; ks < KSH; ++ks)
                xf[m][ks] = *(const s8v*)(A + (m * 16 + l15) * Ap + (kh * KSH + ks) * 32 + l4 * 8);
        #pragma unroll
        for (int i = 0; i < NTW; ++i) {
            const int nt = wid + (ntBase + i) * 4;
            s8v wf[KSH];
            if (kh == 0 && i == 0) {
                #pragma unroll
                for (int ks = 0; ks < KSH; ++ks) wf[ks] = pre.w[ks];
            } else {
                #pragma unroll
                for (int ks = 0; ks < KSH; ++ks)
                    wf[ks] = *(const s8v*)(Wp + nt * (KS * 512) + (kh * KSH + ks) * 512 + lane * 8);
            }
            #pragma unroll
            for (int m = 0; m < MT; ++m)
                #pragma unroll
                for (int ks = 0; ks < KSH; ++ks)
                    acc[i][m] = __builtin_amdgcn_mfma_f32_16x16x32_bf16(wf[ks], xf[m][ks], acc[i][m], 0, 0, 0);
        }
    }
    #pragma unroll
    for (int i = 0; i < NTW; ++i) {
        const int nt = wid + (ntBase + i) * 4;
        const int n0 = nt * 16 + l4 * 4;
        f4v bv = *(const f4v*)(bias + n0);
        #pragma unroll
        for (int m = 0; m < MT; ++m)
            epi_store<EPI>(acc[i][m], bv, m * 16 + l15, n0, Out, Op, aux);
    }
}

// ---- LayerNorm: 4 threads/token, 192 active, 16 elems/thread ----
__device__ __forceinline__ void ln_phase(const float* CH, short* dst, int dp,
                                         const float* __restrict__ g,
                                         const float* __restrict__ b, int tid)
{
    if (tid < 192) {
        int t = tid >> 2, p = tid & 3;
        const float* cp = CH + t * 68 + p * 16;
        f4v c[4];
        #pragma unroll
        for (int i = 0; i < 4; ++i) c[i] = *(const f4v*)(cp + i * 4);
        float s = 0.f, ss = 0.f;
        #pragma unroll
        for (int i = 0; i < 4; ++i)
            #pragma unroll
            for (int j = 0; j < 4; ++j) { float v = c[i][j]; s += v; ss += v * v; }
        s += __shfl_xor(s, 1); ss += __shfl_xor(ss, 1);
        s += __shfl_xor(s, 2); ss += __shfl_xor(ss, 2);
        float mu = s * (1.0f / 64.0f);
        float var = ss * (1.0f / 64.0f) - mu * mu;
        float rstd = rsqrtf(var + 1e-5f);
        int pk[8];
        #pragma unroll
        for (int i = 0; i < 4; ++i) {
            f4v gv = *(const f4v*)(g + p * 16 + i * 4);
            f4v bvv = *(const f4v*)(b + p * 16 + i * 4);
            float o0 = (c[i][0] - mu) * rstd * gv[0] + bvv[0];
            float o1 = (c[i][1] - mu) * rstd * gv[1] + bvv[1];
            float o2 = (c[i][2] - mu) * rstd * gv[2] + bvv[2];
            float o3 = (c[i][3] - mu) * rstd * gv[3] + bvv[3];
            pk[i * 2]     = cvt_pk_bf16(o0, o1);
            pk[i * 2 + 1] = cvt_pk_bf16(o2, o3);
        }
        i4v w0 = {pk[0], pk[1], pk[2], pk[3]};
        i4v w1 = {pk[4], pk[5], pk[6], pk[7]};
        *(i4v*)(dst + t * dp + p * 16) = w0;
        *(i4v*)(dst + t * dp + p * 16 + 8) = w1;
    }
}

// ---- LDS: two ping-pong arenas of 25344 B ----
#define ARENA 25344
#define LDS_BYTES (2 * ARENA)

__global__ __launch_bounds__(256, 3)
void towers_mfma(const float* __restrict__ x,
                 const float* __restrict__ pos_d, const float* __restrict__ pos_c,
                 const float* __restrict__ tb1, const float* __restrict__ tb2,
                 const float* __restrict__ tb3,
                 const float* __restrict__ ln1g, const float* __restrict__ ln1b,
                 const float* __restrict__ inpb, const float* __restrict__ outb,
                 const float* __restrict__ ln2g, const float* __restrict__ ln2b,
                 const float* __restrict__ ffb1, const float* __restrict__ ffb2,
                 const float* __restrict__ hb1, const float* __restrict__ hb2,
                 const float* __restrict__ hw3, const float* __restrict__ hb3,
                 const short* __restrict__ wsBp,
                 float* __restrict__ out, int nTiles)
{
    __shared__ __align__(16) char smem[LDS_BYTES];
    char* P = smem;
    char* Q = smem + ARENA;

    const int tid = threadIdx.x;
    const int lane = tid & 63, wid = tid >> 6;

    for (int tile = blockIdx.x; tile < nTiles; tile += gridDim.x) {
        const long long row0 = (long long)tile * 16;

        // ---- stage x -> A0 bf16 [48][40]; digits weights preload ----
        // (overlaps with previous tile's final dot, which reads P only)
        short* A0 = (short*)Q;
        PreW<1> preBD = preloadW<1>(wsBp + OFF_BD, lane, wid, 1);
        {
            const float* gx = x + row0 * 90;
            for (int i = tid; i < 720; i += 256) {
                int r = i / 45, p = i - r * 45;
                int c = p / 15, kk = (p - c * 15) * 2;
                float2 v = *(const float2*)(gx + r * 90 + p * 2);
                *(int*)(A0 + (r * 3 + c) * 40 + kk) = cvt_pk_bf16(v.x, v.y);
            }
            for (int i = tid; i < 48; i += 256)
                *(int*)(A0 + i * 40 + 30) = 0;   // k=30,31 pad
        }
        BARRIER();   // also fences prev tile's part (P) reads vs A1 writes

        // ---- digits via MFMA: A0(Q) -> A1(P) [48][104] ----
        short* A1 = (short*)P;
        mfma_T<3, 1, 4>(wsBp + OFF_BD, nullptr, A0, 40, A1, 104, 96, pos_d, lane, wid, preBD);
        PreW<3> preT1 = preloadW<3>(wsBp + OFF_TW1, lane, wid, 3);
        BARRIER();

        // ---- tower ----
        short* H1 = (short*)Q;                   // [48][264]
        short* H2 = (short*)P;                   // [48][264]
        float* CH = (float*)Q;                   // [48][68] f32
        mfma_T<3, 3, 0>(wsBp + OFF_TW1, tb1, A1, 104, H1, 264, 256, nullptr, lane, wid, preT1);
        PreW<4> preT2 = preloadW<4>(wsBp + OFF_TW2, lane, wid, 8);
        BARRIER();
        mfma_acc<3, 4, 2, 2, 0>(wsBp + OFF_TW2, tb2, H1, 264, H2, 264, nullptr, lane, wid, 0, preT2);
        {
            PreW<4> preT2b = preloadW<4>(wsBp + OFF_TW2, lane, wid + 8, 8);
            mfma_acc<3, 4, 2, 2, 0>(wsBp + OFF_TW2, tb2, H1, 264, H2, 264, nullptr, lane, wid, 2, preT2b);
        }
        PreW<4> preT3 = preloadW<4>(wsBp + OFF_TW3, lane, wid, 8);
        BARRIER();
        mfma_acc<3, 4, 2, 1, 3>(wsBp + OFF_TW3, tb3, H2, 264, CH, 68, pos_c, lane, wid, 0, preT3);
        PreW<2> preINP = preloadW<2>(wsBp + OFF_INP, lane, wid, 2);
        BARRIER();

        // ---- ln1 ----
        short* aln = (short*)(Q + 13056);        // [48][72]
        ln_phase(CH, aln, 72, ln1g, ln1b, tid);
        BARRIER();

        // ---- qkv ----
        short* qkv = (short*)P;                  // [48][200]
        mfma_T<3, 2, 1>(wsBp + OFF_INP, inpb, aln, 72, qkv, 200, 192, nullptr, lane, wid, preINP);
        PreW<2> preOUT = preloadW<2>(wsBp + OFF_OUT, lane, wid, 2);
        BARRIER();

        // ---- attention ----
        short* ao = (short*)(Q + 13056);         // [48][72]
        if (tid < 192) {
            int r = tid & 15, hc = tid >> 4;
            int h = hc & 3, cq = hc >> 2;
            const short* qp = qkv + (r * 3 + cq) * 200 + h * 16;
            float qv[16];
            { s8v q0 = *(const s8v*)qp, q1 = *(const s8v*)(qp + 8);
              #pragma unroll
              for (int j = 0; j < 8; ++j) {
                  qv[j] = __uint_as_float(((unsigned)(unsigned short)q0[j]) << 16);
                  qv[8 + j] = __uint_as_float(((unsigned)(unsigned short)q1[j]) << 16);
              } }
            float sc[3];
            #pragma unroll
            for (int c = 0; c < 3; ++c) {
                const short* kp = qkv + (r * 3 + c) * 200 + 64 + h * 16;
                s8v k0 = *(const s8v*)kp, k1 = *(const s8v*)(kp + 8);
                float acc = 0.f;
                #pragma unroll
                for (int j = 0; j < 8; ++j) {
                    acc += qv[j] * __uint_as_float(((unsigned)(unsigned short)k0[j]) << 16)
                         + qv[8 + j] * __uint_as_float(((unsigned)(unsigned short)k1[j]) << 16);
                }
                sc[c] = acc * 0.25f;
            }
            float m = fmaxf(sc[0], fmaxf(sc[1], sc[2]));
            float e0 = __expf(sc[0] - m), e1 = __expf(sc[1] - m), e2 = __expf(sc[2] - m);
            float inv = 1.0f / (e0 + e1 + e2);
            e0 *= inv; e1 *= inv; e2 *= inv;
            float ov[16];
            #pragma unroll
            for (int j = 0; j < 16; ++j) ov[j] = 0.f;
            const float ee[3] = {e0, e1, e2};
            #pragma unroll
            for (int c = 0; c < 3; ++c) {
                const short* vp = qkv + (r * 3 + c) * 200 + 128 + h * 16;
                s8v v0 = *(const s8v*)vp, v1 = *(const s8v*)(vp + 8);
                #pragma unroll
                for (int j = 0; j < 8; ++j) {
                    ov[j]     += ee[c] * __uint_as_float(((unsigned)(unsigned short)v0[j]) << 16);
                    ov[8 + j] += ee[c] * __uint_as_float(((unsigned)(unsigned short)v1[j]) << 16);
                }
            }
            short* op = ao + (r * 3 + cq) * 72 + h * 16;
            i4v pk;
            pk[0] = cvt_pk_bf16(ov[0], ov[1]);   pk[1] = cvt_pk_bf16(ov[2], ov[3]);
            pk[2] = cvt_pk_bf16(ov[4], ov[5]);   pk[3] = cvt_pk_bf16(ov[6], ov[7]);
            *(i4v*)op = pk;
            pk[0] = cvt_pk_bf16(ov[8], ov[9]);   pk[1] = cvt_pk_bf16(ov[10], ov[11]);
            pk[2] = cvt_pk_bf16(ov[12], ov[13]); pk[3] = cvt_pk_bf16(ov[14], ov[15]);
            *(i4v*)(op + 8) = pk;
        }
        BARRIER();

        // ---- attn out proj += CH ----
        mfma_T<3, 2, 2>(wsBp + OFF_OUT, outb, ao, 72, CH, 68, 64, nullptr, lane, wid, preOUT);
        PreW<2> preFF1 = preloadW<2>(wsBp + OFF_FF1, lane, wid, 2);
        BARRIER();

        // ---- ln2 ----
        short* fb = (short*)(Q + 13056);
        ln_phase(CH, fb, 72, ln2g, ln2b, tid);
        BARRIER();

        // ---- ffn: ff1 -> g1; ff2 fused residual+flatten -> flat (EPI5) ----
        short* g1 = (short*)P;                   // [48][136]
        mfma_T<3, 2, 0>(wsBp + OFF_FF1, ffb1, fb, 72, g1, 136, 128, nullptr, lane, wid, preFF1);
        PreW<4> preFF2 = preloadW<4>(wsBp + OFF_FF2, lane, wid, 4);
        BARRIER();
        short* flat = (short*)(P + 13312);       // [16][200] bf16
        mfma_T<3, 4, 5>(wsBp + OFF_FF2, ffb2, g1, 136, flat, 200, 64, CH, lane, wid, preFF2);
        PreW<6> preH1 = preloadW<6>(wsBp + OFF_HW1, lane, wid, 6);
        BARRIER();

        // ---- head: hw1 -> hh1; hw2 fused final-dot partials (EPI6) ----
        short* hh1 = (short*)(Q + 13056);        // [16][168]
        mfma_T<1, 6, 0>(wsBp + OFF_HW1, hb1, flat, 200, hh1, 168, 160, nullptr, lane, wid, preH1);
        PreW<5> preH2 = preloadW<5>(wsBp + OFF_HW2, lane, wid, 5);
        BARRIER();
        float* part = (float*)P;                 // [16][16] f32 dot partials
        mfma_T<1, 5, 6>(wsBp + OFF_HW2, hb2, hh1, 168, part, 16, 64, hw3, lane, wid, preH2);
        BARRIER();

        // ---- final dot reduce (reads P only; next tile stages into Q) ----
        if (tid < 64) {
            int r = tid >> 2, p = tid & 3;
            const float* pp = part + r * 16 + p * 4;
            float acc = pp[0] + pp[1] + pp[2] + pp[3];
            acc += __shfl_xor(acc, 1);
            acc += __shfl_xor(acc, 2);
            if (p == 0) out[row0 + r] = acc + hb3[0];
        }
    }
}

extern "C" void kernel_launch(void* const* d_in, const int* in_sizes, int n_in,
                              void* d_out, int out_size, void* d_ws, size_t ws_size,
                              hipStream_t stream) {
    const float* x     = (const float*)d_in[0];
    const float* w_emb = (const float*)d_in[1];
    const float* pos_d = (const float*)d_in[2];
    const float* pos_c = (const float*)d_in[3];
    const float* tw1   = (const float*)d_in[4];
    const float* tb1   = (const float*)d_in[5];
    const float* tw2   = (const float*)d_in[6];
    const float* tb2   = (const float*)d_in[7];
    const float* tw3   = (const float*)d_in[8];
    const float* tb3   = (const float*)d_in[9];
    const float* ln1g  = (const float*)d_in[10];
    const float* ln1b  = (const float*)d_in[11];
    const float* inpw  = (const float*)d_in[12];
    const float* inpb  = (const float*)d_in[13];
    const float* outw  = (const float*)d_in[14];
    const float* outb  = (const float*)d_in[15];
    const float* ln2g  = (const float*)d_in[16];
    const float* ln2b  = (const float*)d_in[17];
    const float* ffw1  = (const float*)d_in[18];
    const float* ffb1  = (const float*)d_in[19];
    const float* ffw2  = (const float*)d_in[20];
    const float* ffb2  = (const float*)d_in[21];
    const float* hw1   = (const float*)d_in[22];
    const float* hb1   = (const float*)d_in[23];
    const float* hw2   = (const float*)d_in[24];
    const float* hb2   = (const float*)d_in[25];
    const float* hw3   = (const float*)d_in[26];
    const float* hb3   = (const float*)d_in[27];
    float* out = (float*)d_out;
    short* wsBp = (short*)d_ws;              // needs 366592 B

    pack_weights<<<dim3(16, 10), 256, 0, stream>>>(w_emb, tw1, tw2, tw3, inpw, outw,
                                                   ffw1, ffw2, hw1, hw2, wsBp);

    const int B = in_sizes[0] / 90;
    const int nTiles = B / 16;               // 8192
    int grid = 768;                          // 3 blocks/CU x 256 CUs
    if (grid > nTiles) grid = nTiles;
    towers_mfma<<<grid, 256, 0, stream>>>(
        x, pos_d, pos_c, tb1, tb2, tb3,
        ln1g, ln1b, inpb, outb, ln2g, ln2b,
        ffb1, ffb2, hb1, hb2, hw3, hb3, wsBp, out, nTiles);
}

// Round 16
// 228.280 us; speedup vs baseline: 1.8739x; 1.8739x over previous
//
#include <hip/hip_runtime.h>
#include <math.h>

// Fused TowersMLP, bf16-MFMA, transposed-D, 256-thread / 4-wave, 3 blocks/CU.
// R16 = R14 (green 247us; 8192-block dispatch RESTORED — persistent grid
// destroyed L2 weight locality, FETCH 26->493MB, retired) + digits/tw1
// ALGEBRAIC FUSION: W' = tw1 @ blockdiag(w_emb) precomputed in pack_weights
// (256x32 bf16) with pos-dependent bias B1[3][256] f32 = tb1 + pos_d @ tw1^T.
// Tower head is now ONE K=32 layer (EPI7: silu(acc+B1[t%3])) — digits phase,
// its barrier, and 2/3 of tw1's K eliminated (~19% of block MFMA work).
// Bias ALWAYS in epilogue (bias-fold into MFMA C is POISON, retired R13).

typedef short s8v __attribute__((ext_vector_type(8)));
typedef float f4v __attribute__((ext_vector_type(4)));
typedef int   i2v __attribute__((ext_vector_type(2)));
typedef int   i4v __attribute__((ext_vector_type(4)));

__device__ __forceinline__ short f2bf(float f) {
    unsigned u = __float_as_uint(f);
    unsigned r = (u + 0x7fffu + ((u >> 16) & 1u)) >> 16;   // RNE
    return (short)r;
}
__device__ __forceinline__ int cvt_pk_bf16(float a, float b) {   // lo=a, hi=b
    int r;
    asm("v_cvt_pk_bf16_f32 %0, %1, %2" : "=v"(r) : "v"(a), "v"(b));
    return r;
}
__device__ __forceinline__ float silu_f(float v) {
    return v * __builtin_amdgcn_rcpf(1.0f + __expf(-v));   // rcp, arg >= 1
}

// lgkm-only barrier (R7 split form — PROVEN; do not combine into one asm).
#define BARRIER() do {                                        \
    asm volatile("s_waitcnt lgkmcnt(0)" ::: "memory");        \
    __builtin_amdgcn_s_barrier();                             \
    __builtin_amdgcn_sched_barrier(0);                        \
} while (0)

// ---- packed weight offsets (bf16 elems), layout [nt][ks][lane(64)][8] ----
#define OFF_T1F  0        // 256 x 32 fused tw1@BD   NT=16 KS=1
#define OFF_TW2  8192     // 256 x 256  NT=16 KS=8
#define OFF_TW3  73728    // 64 x 256   NT=4  KS=8
#define OFF_INP  90112    // 192 x 64   NT=12 KS=2
#define OFF_OUT  102400   // 64 x 64    NT=4  KS=2
#define OFF_FF1  106496   // 128 x 64   NT=8  KS=2
#define OFF_FF2  114688   // 64 x 128   NT=4  KS=4
#define OFF_HW1  122880   // 160 x 192  NT=10 KS=6
#define OFF_HW2  153600   // 64 x 160   NT=4  KS=5
#define BIAS1_ELEM 163840 // f32[3][256] pos-dependent tower bias (3072 B)
// total ws: 163840*2 + 3072 = 330752 B

__global__ void pack_weights(const float* __restrict__ w_emb, const float* __restrict__ tw1,
                             const float* __restrict__ pos_d, const float* __restrict__ tb1,
                             const float* __restrict__ tw2, const float* __restrict__ tw3,
                             const float* __restrict__ inpw, const float* __restrict__ outw,
                             const float* __restrict__ ffw1, const float* __restrict__ ffw2,
                             const float* __restrict__ hw1, const float* __restrict__ hw2,
                             short* __restrict__ dst)
{
    int L = blockIdx.y;
    if (L == 0) {
        // fused W'[n][k] = sum_jj tw1[n][(k/10)*24+jj] * w_emb[jj*10 + k%10], k<30
        int total = 16 * 512;
        for (int e = blockIdx.x * blockDim.x + threadIdx.x; e < total; e += gridDim.x * blockDim.x) {
            int nt = e >> 9, q = e & 511;
            int l = q >> 3, j = q & 7;
            int n = nt * 16 + (l & 15);
            int k = (l >> 4) * 8 + j;
            float v = 0.f;
            if (k < 30) {
                int gl = k / 10, kk = k - gl * 10;
                const float* trow = tw1 + n * 72 + gl * 24;
                for (int jj = 0; jj < 24; ++jj) v += trow[jj] * w_emb[jj * 10 + kk];
            }
            dst[OFF_T1F + e] = f2bf(v);
        }
        return;
    }
    if (L == 9) {
        // B1[pos][n] = tb1[n] + sum_j tw1[n][j] * pos_d[pos*3 + j/24][j%24]
        float* b1 = (float*)(dst + BIAS1_ELEM);
        for (int e = blockIdx.x * blockDim.x + threadIdx.x; e < 768; e += gridDim.x * blockDim.x) {
            int pos = e >> 8, n = e & 255;
            float v = tb1[n];
            for (int j = 0; j < 72; ++j)
                v += tw1[n * 72 + j] * pos_d[(pos * 3 + j / 24) * 24 + (j % 24)];
            b1[e] = v;
        }
        return;
    }
    const float* W; int K, KS, N, off;
    switch (L) {
      case 1: W = tw2;  K = 256; KS = 8; N = 256; off = OFF_TW2; break;
      case 2: W = tw3;  K = 256; KS = 8; N = 64;  off = OFF_TW3; break;
      case 3: W = inpw; K = 64;  KS = 2; N = 192; off = OFF_INP; break;
      case 4: W = outw; K = 64;  KS = 2; N = 64;  off = OFF_OUT; break;
      case 5: W = ffw1; K = 64;  KS = 2; N = 128; off = OFF_FF1; break;
      case 6: W = ffw2; K = 128; KS = 4; N = 64;  off = OFF_FF2; break;
      case 7: W = hw1;  K = 192; KS = 6; N = 160; off = OFF_HW1; break;
      default:W = hw2;  K = 160; KS = 5; N = 64;  off = OFF_HW2; break;
    }
    int total = (N >> 4) * KS * 512;
    for (int e = blockIdx.x * blockDim.x + threadIdx.x; e < total; e += gridDim.x * blockDim.x) {
        int nt = e / (KS * 512);
        int r  = e - nt * (KS * 512);
        int ks = r >> 9;
        int q  = r & 511;
        int l  = q >> 3, j = q & 7;
        int n  = nt * 16 + (l & 15);
        int k  = ks * 32 + (l >> 4) * 8 + j;
        dst[off + e] = f2bf((k < K) ? W[n * K + k] : 0.0f);
    }
}

// ---- weight preload (first-tile fragments held across barriers) ----
template<int KSH> struct PreW { s8v w[KSH]; };

template<int KSH>
__device__ __forceinline__ PreW<KSH> preloadW(const short* __restrict__ Wp,
                                              int lane, int nt, int ksTotal) {
    PreW<KSH> p;
    #pragma unroll
    for (int ks = 0; ks < KSH; ++ks)
        p.w[ks] = *(const s8v*)(Wp + nt * (ksTotal * 512) + ks * 512 + lane * 8);
    return p;
}

// ---- shared epilogue (bias added HERE — never in MFMA C) ----
// EPI: 0 silu->bf16, 1 linear->bf16, 2 f32 +=, 3 f32 = acc+bias+pos_c,
//      5 residual: CH + acc + bias -> flat bf16 [16][200],
//      6 silu(acc+bias) dot hw3 -> f32 partial [16][16],
//      7 silu(acc + B1[t%3]) -> bf16 (fused tower head; bv unused)
template<int EPI>
__device__ __forceinline__ void epi_store(f4v acc, f4v bv, int t, int n0, void* Out, int Op,
                                          const float* __restrict__ aux)
{
    if (EPI == 0 || EPI == 1) {
        float v0 = acc[0] + bv[0], v1 = acc[1] + bv[1];
        float v2 = acc[2] + bv[2], v3 = acc[3] + bv[3];
        if (EPI == 0) { v0 = silu_f(v0); v1 = silu_f(v1); v2 = silu_f(v2); v3 = silu_f(v3); }
        i2v pk; pk[0] = cvt_pk_bf16(v0, v1); pk[1] = cvt_pk_bf16(v2, v3);
        *(i2v*)((short*)Out + t * Op + n0) = pk;
    } else if (EPI == 2) {
        f4v* p = (f4v*)((float*)Out + t * Op + n0);
        f4v o = *p;
        #pragma unroll
        for (int i = 0; i < 4; ++i) o[i] += acc[i] + bv[i];
        *p = o;
    } else if (EPI == 3) {
        f4v pc = *(const f4v*)(aux + (t % 3) * 64 + n0);
        f4v o;
        #pragma unroll
        for (int i = 0; i < 4; ++i) o[i] = acc[i] + bv[i] + pc[i];
        *(f4v*)((float*)Out + t * Op + n0) = o;
    } else if (EPI == 5) {
        // aux = CH f32 [48][68]; Out = flat bf16 [16][Op]
        f4v ch = *(const f4v*)(aux + t * 68 + n0);
        int rr = t / 3, cc = t - rr * 3;
        i2v pk;
        pk[0] = cvt_pk_bf16(ch[0] + acc[0] + bv[0], ch[1] + acc[1] + bv[1]);
        pk[1] = cvt_pk_bf16(ch[2] + acc[2] + bv[2], ch[3] + acc[3] + bv[3]);
        *(i2v*)((short*)Out + rr * Op + cc * 64 + n0) = pk;
    } else if (EPI == 6) {
        // aux = hw3 f32[64]; Out = part f32 [16][16] (Op=16)
        f4v w = *(const f4v*)(aux + n0);
        float p = silu_f(acc[0] + bv[0]) * w[0] + silu_f(acc[1] + bv[1]) * w[1]
                + silu_f(acc[2] + bv[2]) * w[2] + silu_f(acc[3] + bv[3]) * w[3];
        ((float*)Out)[t * Op + (n0 >> 2)] = p;
    } else {
        // EPI 7: aux = B1 f32 [3][256]
        f4v bp = *(const f4v*)(aux + (t % 3) * 256 + n0);
        float v0 = silu_f(acc[0] + bp[0]), v1 = silu_f(acc[1] + bp[1]);
        float v2 = silu_f(acc[2] + bp[2]), v3 = silu_f(acc[3] + bp[3]);
        i2v pk; pk[0] = cvt_pk_bf16(v0, v1); pk[1] = cvt_pk_bf16(v2, v3);
        *(i2v*)((short*)Out + t * Op + n0) = pk;
    }
}

// ---- generic transposed MFMA dense layer, preloaded first tile ----
template<int MT, int KS, int EPI>
__device__ __forceinline__ void mfma_T(
    const short* __restrict__ Wp,
    const float* __restrict__ bias,
    const short* A, int Ap, void* Out, int Op, int N,
    const float* __restrict__ aux, int lane, int wid, PreW<KS> pre)
{
    const int l15 = lane & 15, l4 = lane >> 4;
    s8v xf[MT][KS];
    #pragma unroll
    for (int m = 0; m < MT; ++m)
        #pragma unroll
        for (int ks = 0; ks < KS; ++ks)
            xf[m][ks] = *(const s8v*)(A + (m * 16 + l15) * Ap + ks * 32 + l4 * 8);

    s8v wf[KS];
    #pragma unroll
    for (int ks = 0; ks < KS; ++ks) wf[ks] = pre.w[ks];

    const int NT = N >> 4;
    for (int nt = wid; nt < NT; nt += 4) {
        s8v wfn[KS];
        const bool more = (nt + 4) < NT;
        if (more) {
            #pragma unroll
            for (int ks = 0; ks < KS; ++ks)
                wfn[ks] = *(const s8v*)(Wp + (nt + 4) * (KS * 512) + ks * 512 + lane * 8);
        }
        const int n0 = nt * 16 + l4 * 4;
        f4v bv = {0.f, 0.f, 0.f, 0.f};
        if (EPI != 7) bv = *(const f4v*)(bias + n0);
        #pragma unroll
        for (int m = 0; m < MT; ++m) {
            f4v acc = {0.f, 0.f, 0.f, 0.f};
            #pragma unroll
            for (int ks = 0; ks < KS; ++ks)
                acc = __builtin_amdgcn_mfma_f32_16x16x32_bf16(wf[ks], xf[m][ks], acc, 0, 0, 0);
            epi_store<EPI>(acc, bv, m * 16 + l15, n0, Out, Op, aux);
        }
        if (more) {
            #pragma unroll
            for (int ks = 0; ks < KS; ++ks) wf[ks] = wfn[ks];
        }
    }
}

// ---- K-split persistent-acc layer (tw2/tw3), preloaded (kh=0,i=0) group ----
template<int MT, int KSH, int KH, int NTW, int EPI>
__device__ __forceinline__ void mfma_acc(
    const short* __restrict__ Wp, const float* __restrict__ bias,
    const short* A, int Ap, void* Out, int Op,
    const float* __restrict__ aux, int lane, int wid, int ntBase, PreW<KSH> pre)
{
    const int l15 = lane & 15, l4 = lane >> 4;
    const int KS = KSH * KH;
    f4v acc[NTW][MT];
    #pragma unroll
    for (int i = 0; i < NTW; ++i)
        #pragma unroll
        for (int m = 0; m < MT; ++m) acc[i][m] = (f4v){0.f, 0.f, 0.f, 0.f};

    #pragma unroll
    for (int kh = 0; kh < KH; ++kh) {
        s8v xf[MT][KSH];
        #pragma unroll
        for (int m = 0; m < MT; ++m)
            #pragma unroll
            for (int ks = 0; ks < KSH; ++ks)
                xf[m][ks] = *(const s8v*)(A + (m * 16 + l15) * Ap + (kh * KSH + ks) * 32 + l4 * 8);
        #pragma unroll
        for (int i = 0; i < NTW; ++i) {
            const int nt = wid + (ntBase + i) * 4;
            s8v wf[KSH];
            if (kh == 0 && i == 0) {
                #pragma unroll
                for (int ks = 0; ks < KSH; ++ks) wf[ks] = pre.w[ks];
            } else {
                #pragma unroll
                for (int ks = 0; ks < KSH; ++ks)
                    wf[ks] = *(const s8v*)(Wp + nt * (KS * 512) + (kh * KSH + ks) * 512 + lane * 8);
            }
            #pragma unroll
            for (int m = 0; m < MT; ++m)
                #pragma unroll
                for (int ks = 0; ks < KSH; ++ks)
                    acc[i][m] = __builtin_amdgcn_mfma_f32_16x16x32_bf16(wf[ks], xf[m][ks], acc[i][m], 0, 0, 0);
        }
    }
    #pragma unroll
    for (int i = 0; i < NTW; ++i) {
        const int nt = wid + (ntBase + i) * 4;
        const int n0 = nt * 16 + l4 * 4;
        f4v bv = *(const f4v*)(bias + n0);
        #pragma unroll
        for (int m = 0; m < MT; ++m)
            epi_store<EPI>(acc[i][m], bv, m * 16 + l15, n0, Out, Op, aux);
    }
}

// ---- LayerNorm: 4 threads/token, 192 active, 16 elems/thread ----
__device__ __forceinline__ void ln_phase(const float* CH, short* dst, int dp,
                                         const float* __restrict__ g,
                                         const float* __restrict__ b, int tid)
{
    if (tid < 192) {
        int t = tid >> 2, p = tid & 3;
        const float* cp = CH + t * 68 + p * 16;
        f4v c[4];
        #pragma unroll
        for (int i = 0; i < 4; ++i) c[i] = *(const f4v*)(cp + i * 4);
        float s = 0.f, ss = 0.f;
        #pragma unroll
        for (int i = 0; i < 4; ++i)
            #pragma unroll
            for (int j = 0; j < 4; ++j) { float v = c[i][j]; s += v; ss += v * v; }
        s += __shfl_xor(s, 1); ss += __shfl_xor(ss, 1);
        s += __shfl_xor(s, 2); ss += __shfl_xor(ss, 2);
        float mu = s * (1.0f / 64.0f);
        float var = ss * (1.0f / 64.0f) - mu * mu;
        float rstd = rsqrtf(var + 1e-5f);
        int pk[8];
        #pragma unroll
        for (int i = 0; i < 4; ++i) {
            f4v gv = *(const f4v*)(g + p * 16 + i * 4);
            f4v bvv = *(const f4v*)(b + p * 16 + i * 4);
            float o0 = (c[i][0] - mu) * rstd * gv[0] + bvv[0];
            float o1 = (c[i][1] - mu) * rstd * gv[1] + bvv[1];
            float o2 = (c[i][2] - mu) * rstd * gv[2] + bvv[2];
            float o3 = (c[i][3] - mu) * rstd * gv[3] + bvv[3];
            pk[i * 2]     = cvt_pk_bf16(o0, o1);
            pk[i * 2 + 1] = cvt_pk_bf16(o2, o3);
        }
        i4v w0 = {pk[0], pk[1], pk[2], pk[3]};
        i4v w1 = {pk[4], pk[5], pk[6], pk[7]};
        *(i4v*)(dst + t * dp + p * 16) = w0;
        *(i4v*)(dst + t * dp + p * 16 + 8) = w1;
    }
}

// ---- LDS: two ping-pong arenas of 25344 B ----
#define ARENA 25344
#define LDS_BYTES (2 * ARENA)

__global__ __launch_bounds__(256, 3)
void towers_mfma(const float* __restrict__ x,
                 const float* __restrict__ pos_c,
                 const float* __restrict__ tb2, const float* __restrict__ tb3,
                 const float* __restrict__ ln1g, const float* __restrict__ ln1b,
                 const float* __restrict__ inpb, const float* __restrict__ outb,
                 const float* __restrict__ ln2g, const float* __restrict__ ln2b,
                 const float* __restrict__ ffb1, const float* __restrict__ ffb2,
                 const float* __restrict__ hb1, const float* __restrict__ hb2,
                 const float* __restrict__ hw3, const float* __restrict__ hb3,
                 const short* __restrict__ wsBp,
                 float* __restrict__ out)
{
    __shared__ __align__(16) char smem[LDS_BYTES];
    char* P = smem;
    char* Q = smem + ARENA;

    const int tid = threadIdx.x;
    const int lane = tid & 63, wid = tid >> 6;
    const long long row0 = (long long)blockIdx.x * 16;
    const float* bias1 = (const float*)(wsBp + BIAS1_ELEM);

    // ---- stage x -> A0 bf16 [48][40]; fused-tower weights preload ----
    short* A0 = (short*)Q;
    PreW<1> preT1f = preloadW<1>(wsBp + OFF_T1F, lane, wid, 1);
    {
        const float* gx = x + row0 * 90;
        for (int i = tid; i < 720; i += 256) {
            int r = i / 45, p = i - r * 45;
            int c = p / 15, kk = (p - c * 15) * 2;
            float2 v = *(const float2*)(gx + r * 90 + p * 2);
            *(int*)(A0 + (r * 3 + c) * 40 + kk) = cvt_pk_bf16(v.x, v.y);
        }
        for (int i = tid; i < 48; i += 256)
            *(int*)(A0 + i * 40 + 30) = 0;   // k=30,31 pad (W' zero there, but keep clean)
    }
    BARRIER();

    // ---- fused tower layer 1: A0(Q) -> H1(P) [48][264], EPI7 ----
    short* H1 = (short*)P;
    mfma_T<3, 1, 7>(wsBp + OFF_T1F, nullptr, A0, 40, H1, 264, 256, bias1, lane, wid, preT1f);
    PreW<4> preT2 = preloadW<4>(wsBp + OFF_TW2, lane, wid, 8);
    BARRIER();

    // ---- tw2: H1(P) -> H2(Q) ----
    short* H2 = (short*)Q;
    mfma_acc<3, 4, 2, 2, 0>(wsBp + OFF_TW2, tb2, H1, 264, H2, 264, nullptr, lane, wid, 0, preT2);
    {
        PreW<4> preT2b = preloadW<4>(wsBp + OFF_TW2, lane, wid + 8, 8);
        mfma_acc<3, 4, 2, 2, 0>(wsBp + OFF_TW2, tb2, H1, 264, H2, 264, nullptr, lane, wid, 2, preT2b);
    }
    PreW<4> preT3 = preloadW<4>(wsBp + OFF_TW3, lane, wid, 8);
    BARRIER();

    // ---- tw3: H2(Q) -> CH(P) f32 [48][68] ----
    float* CH = (float*)P;
    mfma_acc<3, 4, 2, 1, 3>(wsBp + OFF_TW3, tb3, H2, 264, CH, 68, pos_c, lane, wid, 0, preT3);
    PreW<2> preINP = preloadW<2>(wsBp + OFF_INP, lane, wid, 2);
    BARRIER();

    // ---- ln1: CH(P) -> aln(P+13056) ----
    short* aln = (short*)(P + 13056);        // [48][72]
    ln_phase(CH, aln, 72, ln1g, ln1b, tid);
    BARRIER();

    // ---- qkv: aln(P+13056) -> qkv(Q) ----
    short* qkv = (short*)Q;                  // [48][200]
    mfma_T<3, 2, 1>(wsBp + OFF_INP, inpb, aln, 72, qkv, 200, 192, nullptr, lane, wid, preINP);
    PreW<2> preOUT = preloadW<2>(wsBp + OFF_OUT, lane, wid, 2);
    BARRIER();

    // ---- attention: qkv(Q) -> ao(P+13056) ----
    short* ao = (short*)(P + 13056);         // [48][72]
    if (tid < 192) {
        int r = tid & 15, hc = tid >> 4;
        int h = hc & 3, cq = hc >> 2;
        const short* qp = qkv + (r * 3 + cq) * 200 + h * 16;
        float qv[16];
        { s8v q0 = *(const s8v*)qp, q1 = *(const s8v*)(qp + 8);
          #pragma unroll
          for (int j = 0; j < 8; ++j) {
              qv[j] = __uint_as_float(((unsigned)(unsigned short)q0[j]) << 16);
              qv[8 + j] = __uint_as_float(((unsigned)(unsigned short)q1[j]) << 16);
          } }
        float sc[3];
        #pragma unroll
        for (int c = 0; c < 3; ++c) {
            const short* kp = qkv + (r * 3 + c) * 200 + 64 + h * 16;
            s8v k0 = *(const s8v*)kp, k1 = *(const s8v*)(kp + 8);
            float acc = 0.f;
            #pragma unroll
            for (int j = 0; j < 8; ++j) {
                acc += qv[j] * __uint_as_float(((unsigned)(unsigned short)k0[j]) << 16)
                     + qv[8 + j] * __uint_as_float(((unsigned)(unsigned short)k1[j]) << 16);
            }
            sc[c] = acc * 0.25f;
        }
        float m = fmaxf(sc[0], fmaxf(sc[1], sc[2]));
        float e0 = __expf(sc[0] - m), e1 = __expf(sc[1] - m), e2 = __expf(sc[2] - m);
        float inv = 1.0f / (e0 + e1 + e2);
        e0 *= inv; e1 *= inv; e2 *= inv;
        float ov[16];
        #pragma unroll
        for (int j = 0; j < 16; ++j) ov[j] = 0.f;
        const float ee[3] = {e0, e1, e2};
        #pragma unroll
        for (int c = 0; c < 3; ++c) {
            const short* vp = qkv + (r * 3 + c) * 200 + 128 + h * 16;
            s8v v0 = *(const s8v*)vp, v1 = *(const s8v*)(vp + 8);
            #pragma unroll
            for (int j = 0; j < 8; ++j) {
                ov[j]     += ee[c] * __uint_as_float(((unsigned)(unsigned short)v0[j]) << 16);
                ov[8 + j] += ee[c] * __uint_as_float(((unsigned)(unsigned short)v1[j]) << 16);
            }
        }
        short* op = ao + (r * 3 + cq) * 72 + h * 16;
        i4v pk;
        pk[0] = cvt_pk_bf16(ov[0], ov[1]);   pk[1] = cvt_pk_bf16(ov[2], ov[3]);
        pk[2] = cvt_pk_bf16(ov[4], ov[5]);   pk[3] = cvt_pk_bf16(ov[6], ov[7]);
        *(i4v*)op = pk;
        pk[0] = cvt_pk_bf16(ov[8], ov[9]);   pk[1] = cvt_pk_bf16(ov[10], ov[11]);
        pk[2] = cvt_pk_bf16(ov[12], ov[13]); pk[3] = cvt_pk_bf16(ov[14], ov[15]);
        *(i4v*)(op + 8) = pk;
    }
    BARRIER();

    // ---- attn out proj: ao(P+13056) += CH(P) ----
    mfma_T<3, 2, 2>(wsBp + OFF_OUT, outb, ao, 72, CH, 68, 64, nullptr, lane, wid, preOUT);
    PreW<2> preFF1 = preloadW<2>(wsBp + OFF_FF1, lane, wid, 2);
    BARRIER();

    // ---- ln2: CH(P) -> fb(P+13056) ----
    short* fb = (short*)(P + 13056);
    ln_phase(CH, fb, 72, ln2g, ln2b, tid);
    BARRIER();

    // ---- ffn: ff1 fb(P+13056) -> g1(Q); ff2 EPI5 -> flat(Q+13312) ----
    short* g1 = (short*)Q;                   // [48][136]
    mfma_T<3, 2, 0>(wsBp + OFF_FF1, ffb1, fb, 72, g1, 136, 128, nullptr, lane, wid, preFF1);
    PreW<4> preFF2 = preloadW<4>(wsBp + OFF_FF2, lane, wid, 4);
    BARRIER();
    short* flat = (short*)(Q + 13312);       // [16][200] bf16
    mfma_T<3, 4, 5>(wsBp + OFF_FF2, ffb2, g1, 136, flat, 200, 64, CH, lane, wid, preFF2);
    PreW<6> preH1 = preloadW<6>(wsBp + OFF_HW1, lane, wid, 6);
    BARRIER();

    // ---- head: hw1 flat(Q+13312) -> hh1(P+13056); hw2 EPI6 -> part(Q) ----
    short* hh1 = (short*)(P + 13056);        // [16][168]
    mfma_T<1, 6, 0>(wsBp + OFF_HW1, hb1, flat, 200, hh1, 168, 160, nullptr, lane, wid, preH1);
    PreW<5> preH2 = preloadW<5>(wsBp + OFF_HW2, lane, wid, 5);
    BARRIER();
    float* part = (float*)Q;                 // [16][16] f32 dot partials
    mfma_T<1, 5, 6>(wsBp + OFF_HW2, hb2, hh1, 168, part, 16, 64, hw3, lane, wid, preH2);
    BARRIER();

    // ---- final dot reduce ----
    if (tid < 64) {
        int r = tid >> 2, p = tid & 3;
        const float* pp = part + r * 16 + p * 4;
        float acc = pp[0] + pp[1] + pp[2] + pp[3];
        acc += __shfl_xor(acc, 1);
        acc += __shfl_xor(acc, 2);
        if (p == 0) out[row0 + r] = acc + hb3[0];
    }
}

extern "C" void kernel_launch(void* const* d_in, const int* in_sizes, int n_in,
                              void* d_out, int out_size, void* d_ws, size_t ws_size,
                              hipStream_t stream) {
    const float* x     = (const float*)d_in[0];
    const float* w_emb = (const float*)d_in[1];
    const float* pos_d = (const float*)d_in[2];
    const float* pos_c = (const float*)d_in[3];
    const float* tw1   = (const float*)d_in[4];
    const float* tb1   = (const float*)d_in[5];
    const float* tw2   = (const float*)d_in[6];
    const float* tb2   = (const float*)d_in[7];
    const float* tw3   = (const float*)d_in[8];
    const float* tb3   = (const float*)d_in[9];
    const float* ln1g  = (const float*)d_in[10];
    const float* ln1b  = (const float*)d_in[11];
    const float* inpw  = (const float*)d_in[12];
    const float* inpb  = (const float*)d_in[13];
    const float* outw  = (const float*)d_in[14];
    const float* outb  = (const float*)d_in[15];
    const float* ln2g  = (const float*)d_in[16];
    const float* ln2b  = (const float*)d_in[17];
    const float* ffw1  = (const float*)d_in[18];
    const float* ffb1  = (const float*)d_in[19];
    const float* ffw2  = (const float*)d_in[20];
    const float* ffb2  = (const float*)d_in[21];
    const float* hw1   = (const float*)d_in[22];
    const float* hb1   = (const float*)d_in[23];
    const float* hw2   = (const float*)d_in[24];
    const float* hb2   = (const float*)d_in[25];
    const float* hw3   = (const float*)d_in[26];
    const float* hb3   = (const float*)d_in[27];
    float* out = (float*)d_out;
    short* wsBp = (short*)d_ws;              // needs 330752 B

    pack_weights<<<dim3(16, 10), 256, 0, stream>>>(w_emb, tw1, pos_d, tb1,
                                                   tw2, tw3, inpw, outw,
                                                   ffw1, ffw2, hw1, hw2, wsBp);

    const int B = in_sizes[0] / 90;
    towers_mfma<<<B / 16, 256, 0, stream>>>(
        x, pos_c, tb2, tb3,
        ln1g, ln1b, inpb, outb, ln2g, ln2b,
        ffb1, ffb2, hb1, hb2, hw3, hb3, wsBp, out);
}

// Round 17
// 226.522 us; speedup vs baseline: 1.8884x; 1.0078x over previous
//
#include <hip/hip_runtime.h>
#include <math.h>

// Fused TowersMLP, bf16-MFMA, transposed-D, 256-thread / 4-wave, 3 blocks/CU.
// R17 = R16 (green 228us: digits/tw1 algebraic fusion, EPI5/6, rcp-silu,
// split lgkm barrier; bias-fold POISON retired; persistent-grid retired)
// + REGISTER-DIRECT x LOADS for the fused first layer: T1F builds its
// A-fragments straight from global x (8B-aligned float2, tail predicated),
// deleting the x-staging loop, the A0 LDS buffer, and barrier #1.

typedef short s8v __attribute__((ext_vector_type(8)));
typedef float f4v __attribute__((ext_vector_type(4)));
typedef int   i2v __attribute__((ext_vector_type(2)));
typedef int   i4v __attribute__((ext_vector_type(4)));

__device__ __forceinline__ short f2bf(float f) {
    unsigned u = __float_as_uint(f);
    unsigned r = (u + 0x7fffu + ((u >> 16) & 1u)) >> 16;   // RNE
    return (short)r;
}
__device__ __forceinline__ int cvt_pk_bf16(float a, float b) {   // lo=a, hi=b
    int r;
    asm("v_cvt_pk_bf16_f32 %0, %1, %2" : "=v"(r) : "v"(a), "v"(b));
    return r;
}
__device__ __forceinline__ float silu_f(float v) {
    return v * __builtin_amdgcn_rcpf(1.0f + __expf(-v));   // rcp, arg >= 1
}

// lgkm-only barrier (R7 split form — PROVEN; do not combine into one asm).
#define BARRIER() do {                                        \
    asm volatile("s_waitcnt lgkmcnt(0)" ::: "memory");        \
    __builtin_amdgcn_s_barrier();                             \
    __builtin_amdgcn_sched_barrier(0);                        \
} while (0)

// ---- packed weight offsets (bf16 elems), layout [nt][ks][lane(64)][8] ----
#define OFF_T1F  0        // 256 x 32 fused tw1@BD   NT=16 KS=1
#define OFF_TW2  8192     // 256 x 256  NT=16 KS=8
#define OFF_TW3  73728    // 64 x 256   NT=4  KS=8
#define OFF_INP  90112    // 192 x 64   NT=12 KS=2
#define OFF_OUT  102400   // 64 x 64    NT=4  KS=2
#define OFF_FF1  106496   // 128 x 64   NT=8  KS=2
#define OFF_FF2  114688   // 64 x 128   NT=4  KS=4
#define OFF_HW1  122880   // 160 x 192  NT=10 KS=6
#define OFF_HW2  153600   // 64 x 160   NT=4  KS=5
#define BIAS1_ELEM 163840 // f32[3][256] pos-dependent tower bias (3072 B)
// total ws: 163840*2 + 3072 = 330752 B

__global__ void pack_weights(const float* __restrict__ w_emb, const float* __restrict__ tw1,
                             const float* __restrict__ pos_d, const float* __restrict__ tb1,
                             const float* __restrict__ tw2, const float* __restrict__ tw3,
                             const float* __restrict__ inpw, const float* __restrict__ outw,
                             const float* __restrict__ ffw1, const float* __restrict__ ffw2,
                             const float* __restrict__ hw1, const float* __restrict__ hw2,
                             short* __restrict__ dst)
{
    int L = blockIdx.y;
    if (L == 0) {
        // fused W'[n][k] = sum_jj tw1[n][(k/10)*24+jj] * w_emb[jj*10 + k%10], k<30
        int total = 16 * 512;
        for (int e = blockIdx.x * blockDim.x + threadIdx.x; e < total; e += gridDim.x * blockDim.x) {
            int nt = e >> 9, q = e & 511;
            int l = q >> 3, j = q & 7;
            int n = nt * 16 + (l & 15);
            int k = (l >> 4) * 8 + j;
            float v = 0.f;
            if (k < 30) {
                int gl = k / 10, kk = k - gl * 10;
                const float* trow = tw1 + n * 72 + gl * 24;
                for (int jj = 0; jj < 24; ++jj) v += trow[jj] * w_emb[jj * 10 + kk];
            }
            dst[OFF_T1F + e] = f2bf(v);
        }
        return;
    }
    if (L == 9) {
        // B1[pos][n] = tb1[n] + sum_j tw1[n][j] * pos_d[pos*3 + j/24][j%24]
        float* b1 = (float*)(dst + BIAS1_ELEM);
        for (int e = blockIdx.x * blockDim.x + threadIdx.x; e < 768; e += gridDim.x * blockDim.x) {
            int pos = e >> 8, n = e & 255;
            float v = tb1[n];
            for (int j = 0; j < 72; ++j)
                v += tw1[n * 72 + j] * pos_d[(pos * 3 + j / 24) * 24 + (j % 24)];
            b1[e] = v;
        }
        return;
    }
    const float* W; int K, KS, N, off;
    switch (L) {
      case 1: W = tw2;  K = 256; KS = 8; N = 256; off = OFF_TW2; break;
      case 2: W = tw3;  K = 256; KS = 8; N = 64;  off = OFF_TW3; break;
      case 3: W = inpw; K = 64;  KS = 2; N = 192; off = OFF_INP; break;
      case 4: W = outw; K = 64;  KS = 2; N = 64;  off = OFF_OUT; break;
      case 5: W = ffw1; K = 64;  KS = 2; N = 128; off = OFF_FF1; break;
      case 6: W = ffw2; K = 128; KS = 4; N = 64;  off = OFF_FF2; break;
      case 7: W = hw1;  K = 192; KS = 6; N = 160; off = OFF_HW1; break;
      default:W = hw2;  K = 160; KS = 5; N = 64;  off = OFF_HW2; break;
    }
    int total = (N >> 4) * KS * 512;
    for (int e = blockIdx.x * blockDim.x + threadIdx.x; e < total; e += gridDim.x * blockDim.x) {
        int nt = e / (KS * 512);
        int r  = e - nt * (KS * 512);
        int ks = r >> 9;
        int q  = r & 511;
        int l  = q >> 3, j = q & 7;
        int n  = nt * 16 + (l & 15);
        int k  = ks * 32 + (l >> 4) * 8 + j;
        dst[off + e] = f2bf((k < K) ? W[n * K + k] : 0.0f);
    }
}

// ---- weight preload (first-tile fragments held across barriers) ----
template<int KSH> struct PreW { s8v w[KSH]; };

template<int KSH>
__device__ __forceinline__ PreW<KSH> preloadW(const short* __restrict__ Wp,
                                              int lane, int nt, int ksTotal) {
    PreW<KSH> p;
    #pragma unroll
    for (int ks = 0; ks < KSH; ++ks)
        p.w[ks] = *(const s8v*)(Wp + nt * (ksTotal * 512) + ks * 512 + lane * 8);
    return p;
}

// ---- shared epilogue (bias added HERE — never in MFMA C) ----
// EPI: 0 silu->bf16, 1 linear->bf16, 2 f32 +=, 3 f32 = acc+bias+pos_c,
//      5 residual: CH + acc + bias -> flat bf16 [16][200],
//      6 silu(acc+bias) dot hw3 -> f32 partial [16][16],
//      7 silu(acc + B1[t%3]) -> bf16 (fused tower head; bv unused)
template<int EPI>
__device__ __forceinline__ void epi_store(f4v acc, f4v bv, int t, int n0, void* Out, int Op,
                                          const float* __restrict__ aux)
{
    if (EPI == 0 || EPI == 1) {
        float v0 = acc[0] + bv[0], v1 = acc[1] + bv[1];
        float v2 = acc[2] + bv[2], v3 = acc[3] + bv[3];
        if (EPI == 0) { v0 = silu_f(v0); v1 = silu_f(v1); v2 = silu_f(v2); v3 = silu_f(v3); }
        i2v pk; pk[0] = cvt_pk_bf16(v0, v1); pk[1] = cvt_pk_bf16(v2, v3);
        *(i2v*)((short*)Out + t * Op + n0) = pk;
    } else if (EPI == 2) {
        f4v* p = (f4v*)((float*)Out + t * Op + n0);
        f4v o = *p;
        #pragma unroll
        for (int i = 0; i < 4; ++i) o[i] += acc[i] + bv[i];
        *p = o;
    } else if (EPI == 3) {
        f4v pc = *(const f4v*)(aux + (t % 3) * 64 + n0);
        f4v o;
        #pragma unroll
        for (int i = 0; i < 4; ++i) o[i] = acc[i] + bv[i] + pc[i];
        *(f4v*)((float*)Out + t * Op + n0) = o;
    } else if (EPI == 5) {
        // aux = CH f32 [48][68]; Out = flat bf16 [16][Op]
        f4v ch = *(const f4v*)(aux + t * 68 + n0);
        int rr = t / 3, cc = t - rr * 3;
        i2v pk;
        pk[0] = cvt_pk_bf16(ch[0] + acc[0] + bv[0], ch[1] + acc[1] + bv[1]);
        pk[1] = cvt_pk_bf16(ch[2] + acc[2] + bv[2], ch[3] + acc[3] + bv[3]);
        *(i2v*)((short*)Out + rr * Op + cc * 64 + n0) = pk;
    } else if (EPI == 6) {
        // aux = hw3 f32[64]; Out = part f32 [16][16] (Op=16)
        f4v w = *(const f4v*)(aux + n0);
        float p = silu_f(acc[0] + bv[0]) * w[0] + silu_f(acc[1] + bv[1]) * w[1]
                + silu_f(acc[2] + bv[2]) * w[2] + silu_f(acc[3] + bv[3]) * w[3];
        ((float*)Out)[t * Op + (n0 >> 2)] = p;
    } else {
        // EPI 7: aux = B1 f32 [3][256]
        f4v bp = *(const f4v*)(aux + (t % 3) * 256 + n0);
        float v0 = silu_f(acc[0] + bp[0]), v1 = silu_f(acc[1] + bp[1]);
        float v2 = silu_f(acc[2] + bp[2]), v3 = silu_f(acc[3] + bp[3]);
        i2v pk; pk[0] = cvt_pk_bf16(v0, v1); pk[1] = cvt_pk_bf16(v2, v3);
        *(i2v*)((short*)Out + t * Op + n0) = pk;
    }
}

// ---- generic transposed MFMA dense layer, preloaded first tile ----
template<int MT, int KS, int EPI>
__device__ __forceinline__ void mfma_T(
    const short* __restrict__ Wp,
    const float* __restrict__ bias,
    const short* A, int Ap, void* Out, int Op, int N,
    const float* __restrict__ aux, int lane, int wid, PreW<KS> pre)
{
    const int l15 = lane & 15, l4 = lane >> 4;
    s8v xf[MT][KS];
    #pragma unroll
    for (int m = 0; m < MT; ++m)
        #pragma unroll
        for (int ks = 0; ks < KS; ++ks)
            xf[m][ks] = *(const s8v*)(A + (m * 16 + l15) * Ap + ks * 32 + l4 * 8);

    s8v wf[KS];
    #pragma unroll
    for (int ks = 0; ks < KS; ++ks) wf[ks] = pre.w[ks];

    const int NT = N >> 4;
    for (int nt = wid; nt < NT; nt += 4) {
        s8v wfn[KS];
        const bool more = (nt + 4) < NT;
        if (more) {
            #pragma unroll
            for (int ks = 0; ks < KS; ++ks)
                wfn[ks] = *(const s8v*)(Wp + (nt + 4) * (KS * 512) + ks * 512 + lane * 8);
        }
        const int n0 = nt * 16 + l4 * 4;
        f4v bv = {0.f, 0.f, 0.f, 0.f};
        if (EPI != 7) bv = *(const f4v*)(bias + n0);
        #pragma unroll
        for (int m = 0; m < MT; ++m) {
            f4v acc = {0.f, 0.f, 0.f, 0.f};
            #pragma unroll
            for (int ks = 0; ks < KS; ++ks)
                acc = __builtin_amdgcn_mfma_f32_16x16x32_bf16(wf[ks], xf[m][ks], acc, 0, 0, 0);
            epi_store<EPI>(acc, bv, m * 16 + l15, n0, Out, Op, aux);
        }
        if (more) {
            #pragma unroll
            for (int ks = 0; ks < KS; ++ks) wf[ks] = wfn[ks];
        }
    }
}

// ---- fused first layer: A-fragments loaded DIRECTLY from global x ----
// token t = m*16+l15 -> row r=t/3, chunk c=t%3; k = l4*8+j over x[r][c*30+k],
// k>=30 is zero (W' zero there too, but must not be garbage/NaN).
__device__ __forceinline__ void mfma_x1(
    const short* __restrict__ Wp, const float* __restrict__ x, long long row0,
    void* Out, int Op, const float* __restrict__ bias1,
    int lane, int wid, PreW<1> pre)
{
    const int l15 = lane & 15, l4 = lane >> 4;
    s8v xf[3];
    #pragma unroll
    for (int m = 0; m < 3; ++m) {
        int t = m * 16 + l15;
        int r = t / 3, c = t - r * 3;
        const float* xp = x + (row0 + r) * 90 + c * 30 + l4 * 8;
        float2 a = *(const float2*)xp;
        float2 b = *(const float2*)(xp + 2);
        float2 d = *(const float2*)(xp + 4);
        float2 e = (l4 < 3) ? *(const float2*)(xp + 6) : make_float2(0.f, 0.f);
        i4v pk;
        pk[0] = cvt_pk_bf16(a.x, a.y);
        pk[1] = cvt_pk_bf16(b.x, b.y);
        pk[2] = cvt_pk_bf16(d.x, d.y);
        pk[3] = cvt_pk_bf16(e.x, e.y);
        xf[m] = *(s8v*)&pk;
    }

    s8v wf = pre.w[0];
    for (int nt = wid; nt < 16; nt += 4) {
        s8v wfn;
        const bool more = (nt + 4) < 16;
        if (more) wfn = *(const s8v*)(Wp + (nt + 4) * 512 + lane * 8);
        const int n0 = nt * 16 + l4 * 4;
        #pragma unroll
        for (int m = 0; m < 3; ++m) {
            f4v acc = {0.f, 0.f, 0.f, 0.f};
            acc = __builtin_amdgcn_mfma_f32_16x16x32_bf16(wf, xf[m], acc, 0, 0, 0);
            epi_store<7>(acc, acc, m * 16 + l15, n0, Out, Op, bias1);
        }
        if (more) wf = wfn;
    }
}

// ---- K-split persistent-acc layer (tw2/tw3), preloaded (kh=0,i=0) group ----
template<int MT, int KSH, int KH, int NTW, int EPI>
__device__ __forceinline__ void mfma_acc(
    const short* __restrict__ Wp, const float* __restrict__ bias,
    const short* A, int Ap, void* Out, int Op,
    const float* __restrict__ aux, int lane, int wid, int ntBase, PreW<KSH> pre)
{
    const int l15 = lane & 15, l4 = lane >> 4;
    const int KS = KSH * KH;
    f4v acc[NTW][MT];
    #pragma unroll
    for (int i = 0; i < NTW; ++i)
        #pragma unroll
        for (int m = 0; m < MT; ++m) acc[i][m] = (f4v){0.f, 0.f, 0.f, 0.f};

    #pragma unroll
    for (int kh = 0; kh < KH; ++kh) {
        s8v xf[MT][KSH];
        #pragma unroll
        for (int m = 0; m < MT; ++m)
            #pragma unroll
            for (int ks = 0; ks < KSH; ++ks)
                xf[m][ks] = *(const s8v*)(A + (m * 16 + l15) * Ap + (kh * KSH + ks) * 32 + l4 * 8);
        #pragma unroll
        for (int i = 0; i < NTW; ++i) {
            const int nt = wid + (ntBase + i) * 4;
            s8v wf[KSH];
            if (kh == 0 && i == 0) {
                #pragma unroll
                for (int ks = 0; ks < KSH; ++ks) wf[ks] = pre.w[ks];
            } else {
                #pragma unroll
                for (int ks = 0; ks < KSH; ++ks)
                    wf[ks] = *(const s8v*)(Wp + nt * (KS * 512) + (kh * KSH + ks) * 512 + lane * 8);
            }
            #pragma unroll
            for (int m = 0; m < MT; ++m)
                #pragma unroll
                for (int ks = 0; ks < KSH; ++ks)
                    acc[i][m] = __builtin_amdgcn_mfma_f32_16x16x32_bf16(wf[ks], xf[m][ks], acc[i][m], 0, 0, 0);
        }
    }
    #pragma unroll
    for (int i = 0; i < NTW; ++i) {
        const int nt = wid + (ntBase + i) * 4;
        const int n0 = nt * 16 + l4 * 4;
        f4v bv = *(const f4v*)(bias + n0);
        #pragma unroll
        for (int m = 0; m < MT; ++m)
            epi_store<EPI>(acc[i][m], bv, m * 16 + l15, n0, Out, Op, aux);
    }
}

// ---- LayerNorm: 4 threads/token, 192 active, 16 elems/thread ----
__device__ __forceinline__ void ln_phase(const float* CH, short* dst, int dp,
                                         const float* __restrict__ g,
                                         const float* __restrict__ b, int tid)
{
    if (tid < 192) {
        int t = tid >> 2, p = tid & 3;
        const float* cp = CH + t * 68 + p * 16;
        f4v c[4];
        #pragma unroll
        for (int i = 0; i < 4; ++i) c[i] = *(const f4v*)(cp + i * 4);
        float s = 0.f, ss = 0.f;
        #pragma unroll
        for (int i = 0; i < 4; ++i)
            #pragma unroll
            for (int j = 0; j < 4; ++j) { float v = c[i][j]; s += v; ss += v * v; }
        s += __shfl_xor(s, 1); ss += __shfl_xor(ss, 1);
        s += __shfl_xor(s, 2); ss += __shfl_xor(ss, 2);
        float mu = s * (1.0f / 64.0f);
        float var = ss * (1.0f / 64.0f) - mu * mu;
        float rstd = rsqrtf(var + 1e-5f);
        int pk[8];
        #pragma unroll
        for (int i = 0; i < 4; ++i) {
            f4v gv = *(const f4v*)(g + p * 16 + i * 4);
            f4v bvv = *(const f4v*)(b + p * 16 + i * 4);
            float o0 = (c[i][0] - mu) * rstd * gv[0] + bvv[0];
            float o1 = (c[i][1] - mu) * rstd * gv[1] + bvv[1];
            float o2 = (c[i][2] - mu) * rstd * gv[2] + bvv[2];
            float o3 = (c[i][3] - mu) * rstd * gv[3] + bvv[3];
            pk[i * 2]     = cvt_pk_bf16(o0, o1);
            pk[i * 2 + 1] = cvt_pk_bf16(o2, o3);
        }
        i4v w0 = {pk[0], pk[1], pk[2], pk[3]};
        i4v w1 = {pk[4], pk[5], pk[6], pk[7]};
        *(i4v*)(dst + t * dp + p * 16) = w0;
        *(i4v*)(dst + t * dp + p * 16 + 8) = w1;
    }
}

// ---- LDS: two ping-pong arenas of 25344 B ----
#define ARENA 25344
#define LDS_BYTES (2 * ARENA)

__global__ __launch_bounds__(256, 3)
void towers_mfma(const float* __restrict__ x,
                 const float* __restrict__ pos_c,
                 const float* __restrict__ tb2, const float* __restrict__ tb3,
                 const float* __restrict__ ln1g, const float* __restrict__ ln1b,
                 const float* __restrict__ inpb, const float* __restrict__ outb,
                 const float* __restrict__ ln2g, const float* __restrict__ ln2b,
                 const float* __restrict__ ffb1, const float* __restrict__ ffb2,
                 const float* __restrict__ hb1, const float* __restrict__ hb2,
                 const float* __restrict__ hw3, const float* __restrict__ hb3,
                 const short* __restrict__ wsBp,
                 float* __restrict__ out)
{
    __shared__ __align__(16) char smem[LDS_BYTES];
    char* P = smem;
    char* Q = smem + ARENA;

    const int tid = threadIdx.x;
    const int lane = tid & 63, wid = tid >> 6;
    const long long row0 = (long long)blockIdx.x * 16;
    const float* bias1 = (const float*)(wsBp + BIAS1_ELEM);

    // ---- fused tower layer 1: x(global) -> H1(P) [48][264], EPI7 ----
    short* H1 = (short*)P;
    PreW<1> preT1f = preloadW<1>(wsBp + OFF_T1F, lane, wid, 1);
    mfma_x1(wsBp + OFF_T1F, x, row0, H1, 264, bias1, lane, wid, preT1f);
    PreW<4> preT2 = preloadW<4>(wsBp + OFF_TW2, lane, wid, 8);
    BARRIER();

    // ---- tw2: H1(P) -> H2(Q) ----
    short* H2 = (short*)Q;
    mfma_acc<3, 4, 2, 2, 0>(wsBp + OFF_TW2, tb2, H1, 264, H2, 264, nullptr, lane, wid, 0, preT2);
    {
        PreW<4> preT2b = preloadW<4>(wsBp + OFF_TW2, lane, wid + 8, 8);
        mfma_acc<3, 4, 2, 2, 0>(wsBp + OFF_TW2, tb2, H1, 264, H2, 264, nullptr, lane, wid, 2, preT2b);
    }
    PreW<4> preT3 = preloadW<4>(wsBp + OFF_TW3, lane, wid, 8);
    BARRIER();

    // ---- tw3: H2(Q) -> CH(P) f32 [48][68] ----
    float* CH = (float*)P;
    mfma_acc<3, 4, 2, 1, 3>(wsBp + OFF_TW3, tb3, H2, 264, CH, 68, pos_c, lane, wid, 0, preT3);
    PreW<2> preINP = preloadW<2>(wsBp + OFF_INP, lane, wid, 2);
    BARRIER();

    // ---- ln1: CH(P) -> aln(P+13056) ----
    short* aln = (short*)(P + 13056);        // [48][72]
    ln_phase(CH, aln, 72, ln1g, ln1b, tid);
    BARRIER();

    // ---- qkv: aln(P+13056) -> qkv(Q) ----
    short* qkv = (short*)Q;                  // [48][200]
    mfma_T<3, 2, 1>(wsBp + OFF_INP, inpb, aln, 72, qkv, 200, 192, nullptr, lane, wid, preINP);
    PreW<2> preOUT = preloadW<2>(wsBp + OFF_OUT, lane, wid, 2);
    BARRIER();

    // ---- attention: qkv(Q) -> ao(P+13056) ----
    short* ao = (short*)(P + 13056);         // [48][72]
    if (tid < 192) {
        int r = tid & 15, hc = tid >> 4;
        int h = hc & 3, cq = hc >> 2;
        const short* qp = qkv + (r * 3 + cq) * 200 + h * 16;
        float qv[16];
        { s8v q0 = *(const s8v*)qp, q1 = *(const s8v*)(qp + 8);
          #pragma unroll
          for (int j = 0; j < 8; ++j) {
              qv[j] = __uint_as_float(((unsigned)(unsigned short)q0[j]) << 16);
              qv[8 + j] = __uint_as_float(((unsigned)(unsigned short)q1[j]) << 16);
          } }
        float sc[3];
        #pragma unroll
        for (int c = 0; c < 3; ++c) {
            const short* kp = qkv + (r * 3 + c) * 200 + 64 + h * 16;
            s8v k0 = *(const s8v*)kp, k1 = *(const s8v*)(kp + 8);
            float acc = 0.f;
            #pragma unroll
            for (int j = 0; j < 8; ++j) {
                acc += qv[j] * __uint_as_float(((unsigned)(unsigned short)k0[j]) << 16)
                     + qv[8 + j] * __uint_as_float(((unsigned)(unsigned short)k1[j]) << 16);
            }
            sc[c] = acc * 0.25f;
        }
        float m = fmaxf(sc[0], fmaxf(sc[1], sc[2]));
        float e0 = __expf(sc[0] - m), e1 = __expf(sc[1] - m), e2 = __expf(sc[2] - m);
        float inv = 1.0f / (e0 + e1 + e2);
        e0 *= inv; e1 *= inv; e2 *= inv;
        float ov[16];
        #pragma unroll
        for (int j = 0; j < 16; ++j) ov[j] = 0.f;
        const float ee[3] = {e0, e1, e2};
        #pragma unroll
        for (int c = 0; c < 3; ++c) {
            const short* vp = qkv + (r * 3 + c) * 200 + 128 + h * 16;
            s8v v0 = *(const s8v*)vp, v1 = *(const s8v*)(vp + 8);
            #pragma unroll
            for (int j = 0; j < 8; ++j) {
                ov[j]     += ee[c] * __uint_as_float(((unsigned)(unsigned short)v0[j]) << 16);
                ov[8 + j] += ee[c] * __uint_as_float(((unsigned)(unsigned short)v1[j]) << 16);
            }
        }
        short* op = ao + (r * 3 + cq) * 72 + h * 16;
        i4v pk;
        pk[0] = cvt_pk_bf16(ov[0], ov[1]);   pk[1] = cvt_pk_bf16(ov[2], ov[3]);
        pk[2] = cvt_pk_bf16(ov[4], ov[5]);   pk[3] = cvt_pk_bf16(ov[6], ov[7]);
        *(i4v*)op = pk;
        pk[0] = cvt_pk_bf16(ov[8], ov[9]);   pk[1] = cvt_pk_bf16(ov[10], ov[11]);
        pk[2] = cvt_pk_bf16(ov[12], ov[13]); pk[3] = cvt_pk_bf16(ov[14], ov[15]);
        *(i4v*)(op + 8) = pk;
    }
    BARRIER();

    // ---- attn out proj: ao(P+13056) += CH(P) ----
    mfma_T<3, 2, 2>(wsBp + OFF_OUT, outb, ao, 72, CH, 68, 64, nullptr, lane, wid, preOUT);
    PreW<2> preFF1 = preloadW<2>(wsBp + OFF_FF1, lane, wid, 2);
    BARRIER();

    // ---- ln2: CH(P) -> fb(P+13056) ----
    short* fb = (short*)(P + 13056);
    ln_phase(CH, fb, 72, ln2g, ln2b, tid);
    BARRIER();

    // ---- ffn: ff1 fb(P+13056) -> g1(Q); ff2 EPI5 -> flat(Q+13312) ----
    short* g1 = (short*)Q;                   // [48][136]
    mfma_T<3, 2, 0>(wsBp + OFF_FF1, ffb1, fb, 72, g1, 136, 128, nullptr, lane, wid, preFF1);
    PreW<4> preFF2 = preloadW<4>(wsBp + OFF_FF2, lane, wid, 4);
    BARRIER();
    short* flat = (short*)(Q + 13312);       // [16][200] bf16
    mfma_T<3, 4, 5>(wsBp + OFF_FF2, ffb2, g1, 136, flat, 200, 64, CH, lane, wid, preFF2);
    PreW<6> preH1 = preloadW<6>(wsBp + OFF_HW1, lane, wid, 6);
    BARRIER();

    // ---- head: hw1 flat(Q+13312) -> hh1(P+13056); hw2 EPI6 -> part(Q) ----
    short* hh1 = (short*)(P + 13056);        // [16][168]
    mfma_T<1, 6, 0>(wsBp + OFF_HW1, hb1, flat, 200, hh1, 168, 160, nullptr, lane, wid, preH1);
    PreW<5> preH2 = preloadW<5>(wsBp + OFF_HW2, lane, wid, 5);
    BARRIER();
    float* part = (float*)Q;                 // [16][16] f32 dot partials
    mfma_T<1, 5, 6>(wsBp + OFF_HW2, hb2, hh1, 168, part, 16, 64, hw3, lane, wid, preH2);
    BARRIER();

    // ---- final dot reduce ----
    if (tid < 64) {
        int r = tid >> 2, p = tid & 3;
        const float* pp = part + r * 16 + p * 4;
        float acc = pp[0] + pp[1] + pp[2] + pp[3];
        acc += __shfl_xor(acc, 1);
        acc += __shfl_xor(acc, 2);
        if (p == 0) out[row0 + r] = acc + hb3[0];
    }
}

extern "C" void kernel_launch(void* const* d_in, const int* in_sizes, int n_in,
                              void* d_out, int out_size, void* d_ws, size_t ws_size,
                              hipStream_t stream) {
    const float* x     = (const float*)d_in[0];
    const float* w_emb = (const float*)d_in[1];
    const float* pos_d = (const float*)d_in[2];
    const float* pos_c = (const float*)d_in[3];
    const float* tw1   = (const float*)d_in[4];
    const float* tb1   = (const float*)d_in[5];
    const float* tw2   = (const float*)d_in[6];
    const float* tb2   = (const float*)d_in[7];
    const float* tw3   = (const float*)d_in[8];
    const float* tb3   = (const float*)d_in[9];
    const float* ln1g  = (const float*)d_in[10];
    const float* ln1b  = (const float*)d_in[11];
    const float* inpw  = (const float*)d_in[12];
    const float* inpb  = (const float*)d_in[13];
    const float* outw  = (const float*)d_in[14];
    const float* outb  = (const float*)d_in[15];
    const float* ln2g  = (const float*)d_in[16];
    const float* ln2b  = (const float*)d_in[17];
    const float* ffw1  = (const float*)d_in[18];
    const float* ffb1  = (const float*)d_in[19];
    const float* ffw2  = (const float*)d_in[20];
    const float* ffb2  = (const float*)d_in[21];
    const float* hw1   = (const float*)d_in[22];
    const float* hb1   = (const float*)d_in[23];
    const float* hw2   = (const float*)d_in[24];
    const float* hb2   = (const float*)d_in[25];
    const float* hw3   = (const float*)d_in[26];
    const float* hb3   = (const float*)d_in[27];
    float* out = (float*)d_out;
    short* wsBp = (short*)d_ws;              // needs 330752 B

    pack_weights<<<dim3(16, 10), 256, 0, stream>>>(w_emb, tw1, pos_d, tb1,
                                                   tw2, tw3, inpw, outw,
                                                   ffw1, ffw2, hw1, hw2, wsBp);

    const int B = in_sizes[0] / 90;
    towers_mfma<<<B / 16, 256, 0, stream>>>(
        x, pos_c, tb2, tb3,
        ln1g, ln1b, inpb, outb, ln2g, ln2b,
        ffb1, ffb2, hb1, hb2, hw3, hb3, wsBp, out);
}